// Round 1
// baseline (506.771 us; speedup 1.0000x reference)
//
#include <hip/hip_runtime.h>
#include <hip/hip_bf16.h>
#include <math.h>

#define NN 2048
#define NEG_SLOPE 0.2f

// ---------------------------------------------------------------------------
// K1: agg[s,t] = sum_c conv_w[c]*attn[c,s,t] + conv_b ; store TRANSPOSED:
//     aggT[t][s].  Tiled 64x64 with LDS transpose, coalesced both ways.
// ---------------------------------------------------------------------------
__global__ __launch_bounds__(256) void k_agg(const float* __restrict__ attn,
                                             const float* __restrict__ conv_w,
                                             const float* __restrict__ conv_b,
                                             float* __restrict__ aggT) {
  __shared__ float tile[64][65];
  const int t0 = blockIdx.x * 64;
  const int s0 = blockIdx.y * 64;
  const int tx = threadIdx.x & 63;   // t within tile
  const int ty = threadIdx.x >> 6;   // 0..3
  float w[12];
#pragma unroll
  for (int c = 0; c < 12; ++c) w[c] = conv_w[c];
  const float cb = conv_b[0];
  float acc[16];
#pragma unroll
  for (int i = 0; i < 16; ++i) acc[i] = cb;
  for (int c = 0; c < 12; ++c) {
    const float* base = attn + (size_t)c * NN * NN + (size_t)s0 * NN + t0 + tx;
#pragma unroll
    for (int i = 0; i < 16; ++i) {
      int s = 4 * i + ty;
      acc[i] += w[c] * base[(size_t)s * NN];
    }
  }
#pragma unroll
  for (int i = 0; i < 16; ++i) tile[4 * i + ty][tx] = acc[i];
  __syncthreads();
  const int sx = tx;
#pragma unroll
  for (int i = 0; i < 16; ++i) {
    int t = 4 * i + ty;
    aggT[(size_t)(t0 + t) * NN + s0 + sx] = tile[sx][t];
  }
}

// ---------------------------------------------------------------------------
// K1b: per-target stats over aggT row: mean_attr[t] = sum(masked)/max(cnt,1)
// ---------------------------------------------------------------------------
__global__ __launch_bounds__(256) void k_stats(const float* __restrict__ aggT,
                                               float* __restrict__ mean_attr) {
  const int t = blockIdx.x;
  float sum = 0.f;
  int cnt = 0;
  for (int s = threadIdx.x; s < NN; s += 256) {
    float a = aggT[(size_t)t * NN + s];
    if (a > 0.f && s != t) { sum += a; cnt++; }
  }
  for (int off = 32; off; off >>= 1) {
    sum += __shfl_down(sum, off);
    cnt += __shfl_down(cnt, off);
  }
  __shared__ float swsum[4];
  __shared__ int swcnt[4];
  if ((threadIdx.x & 63) == 0) {
    swsum[threadIdx.x >> 6] = sum;
    swcnt[threadIdx.x >> 6] = cnt;
  }
  __syncthreads();
  if (threadIdx.x == 0) {
    float s = swsum[0] + swsum[1] + swsum[2] + swsum[3];
    int c = swcnt[0] + swcnt[1] + swcnt[2] + swcnt[3];
    mean_attr[t] = s / (float)(c > 1 ? c : 1);
  }
}

// ---------------------------------------------------------------------------
// K_prep: ce1[h] = sum_c att_edge1[h,c]*We1[h*128+c]  (h=0..3), ce[4] = layer2
// ---------------------------------------------------------------------------
__global__ __launch_bounds__(256) void k_prep(const float* __restrict__ ae1,
                                              const float* __restrict__ We1,
                                              const float* __restrict__ ae2,
                                              const float* __restrict__ We2,
                                              float* __restrict__ ce) {
  const int lane = threadIdx.x & 63;
  const int wv = threadIdx.x >> 6;
  float p = ae1[wv * 128 + lane] * We1[wv * 128 + lane] +
            ae1[wv * 128 + 64 + lane] * We1[wv * 128 + 64 + lane];
  for (int off = 32; off; off >>= 1) p += __shfl_down(p, off);
  if (lane == 0) ce[wv] = p;
  float q = ae2[lane] * We2[lane] + ae2[64 + lane] * We2[64 + lane];
  for (int off = 32; off; off >>= 1) q += __shfl_down(q, off);
  if (threadIdx.x == 0) ce[4] = q;
}

// ---------------------------------------------------------------------------
// Generic fp32 GEMM  C[M,N] = A[M,K] @ B[K,N]   (256 threads)
// ---------------------------------------------------------------------------
template <int BM, int BN, int BK, int TM, int TN>
__global__ __launch_bounds__(256) void k_gemm(const float* __restrict__ A,
                                              const float* __restrict__ B,
                                              float* __restrict__ C, int M,
                                              int Nn, int K) {
  __shared__ float As[BK][BM + 4];
  __shared__ float Bs[BK][BN + 4];
  const int tx = threadIdx.x % (BN / TN);
  const int ty = threadIdx.x / (BN / TN);
  const int n0 = blockIdx.x * BN;
  const int m0 = blockIdx.y * BM;
  float acc[TM][TN] = {};
  for (int k0 = 0; k0 < K; k0 += BK) {
    for (int e = threadIdx.x; e < BM * BK; e += 256) {
      int r = e / BK, c = e % BK;
      As[c][r] = A[(size_t)(m0 + r) * K + k0 + c];
    }
    for (int e = threadIdx.x; e < BK * BN; e += 256) {
      int r = e / BN, c = e % BN;
      Bs[r][c] = B[(size_t)(k0 + r) * Nn + n0 + c];
    }
    __syncthreads();
#pragma unroll
    for (int kk = 0; kk < BK; ++kk) {
      float a[TM], b[TN];
#pragma unroll
      for (int i = 0; i < TM; ++i) a[i] = As[kk][ty * TM + i];
#pragma unroll
      for (int j = 0; j < TN; ++j) b[j] = Bs[kk][tx * TN + j];
#pragma unroll
      for (int i = 0; i < TM; ++i)
#pragma unroll
        for (int j = 0; j < TN; ++j) acc[i][j] += a[i] * b[j];
    }
    __syncthreads();
  }
#pragma unroll
  for (int i = 0; i < TM; ++i)
#pragma unroll
    for (int j = 0; j < TN; ++j)
      C[(size_t)(m0 + ty * TM + i) * Nn + n0 + tx * TN + j] = acc[i][j];
}

// ---------------------------------------------------------------------------
// s_src / s_dst per node: dot(h[n, h*128:...], att_vec)
// ---------------------------------------------------------------------------
template <int NH>
__global__ __launch_bounds__(64) void k_srcdst(const float* __restrict__ h,
                                               const float* __restrict__ a_src,
                                               const float* __restrict__ a_dst,
                                               float* __restrict__ ssrc,
                                               float* __restrict__ sdst) {
  const int n = blockIdx.x;
  const int lane = threadIdx.x;
  float ps = 0.f, pd = 0.f;
  if constexpr (NH == 4) {
    const float4* hv = (const float4*)(h + (size_t)n * 512);
    const float4* av = (const float4*)a_src;
    const float4* dv = (const float4*)a_dst;
    float4 v0 = hv[lane * 2], v1 = hv[lane * 2 + 1];
    float4 a0 = av[lane * 2], a1 = av[lane * 2 + 1];
    float4 d0 = dv[lane * 2], d1 = dv[lane * 2 + 1];
    ps = v0.x * a0.x + v0.y * a0.y + v0.z * a0.z + v0.w * a0.w +
         v1.x * a1.x + v1.y * a1.y + v1.z * a1.z + v1.w * a1.w;
    pd = v0.x * d0.x + v0.y * d0.y + v0.z * d0.z + v0.w * d0.w +
         v1.x * d1.x + v1.y * d1.y + v1.z * d1.z + v1.w * d1.w;
    for (int off = 8; off; off >>= 1) {
      ps += __shfl_down(ps, off);
      pd += __shfl_down(pd, off);
    }
    if ((lane & 15) == 0) {
      int hh = lane >> 4;
      ssrc[n * 4 + hh] = ps;
      sdst[n * 4 + hh] = pd;
    }
  } else {
    const float2* hv = (const float2*)(h + (size_t)n * 128);
    const float2* av = (const float2*)a_src;
    const float2* dv = (const float2*)a_dst;
    float2 v = hv[lane];
    float2 a = av[lane];
    float2 d = dv[lane];
    ps = v.x * a.x + v.y * a.y;
    pd = v.x * d.x + v.y * d.y;
    for (int off = 32; off; off >>= 1) {
      ps += __shfl_down(ps, off);
      pd += __shfl_down(pd, off);
    }
    if (lane == 0) {
      ssrc[n] = ps;
      sdst[n] = pd;
    }
  }
}

// ---------------------------------------------------------------------------
// Fused attention-softmax GEMM (numerator + denominator), split-K over s.
//   P[t,s] = adj ? exp(leaky(ssrc[s]+sdst[t]+eattr[t,s]*ce)) : 0
//   num[t,c] += P[t,s]*h[s,c] ;  d[t] += P[t,s]
// Block: 32 targets x 128 channels (one head), 256 threads, micro 4x4.
// ---------------------------------------------------------------------------
template <int NH, int SPLITS>
__global__ __launch_bounds__(256) void k_attn(
    const float* __restrict__ aggT, const float* __restrict__ hfeat,
    const float* __restrict__ ssrc, const float* __restrict__ sdst,
    const float* __restrict__ mean_attr, const float* __restrict__ ce_all,
    float* __restrict__ num, float* __restrict__ dden) {
  constexpr int W = NH * 128;
  constexpr int SLEN = NN / SPLITS;
  const int t0 = blockIdx.x * 32;
  const int h = (NH == 1) ? 0 : blockIdx.y;
  const int split = blockIdx.z;
  const float ce = (NH == 1) ? ce_all[4] : ce_all[h];
  __shared__ float PT[32][36];    // [s_in_tile][t]
  __shared__ float Bs[32][132];   // [s_in_tile][c]
  __shared__ float dloc[32];
  __shared__ float sd_sh[32];
  __shared__ float ma_sh[32];
  const int tid = threadIdx.x;
  if (tid < 32) {
    dloc[tid] = 0.f;
    sd_sh[tid] = sdst[(t0 + tid) * NH + h];
    ma_sh[tid] = mean_attr[t0 + tid];
  }
  __syncthreads();
  const int tx = tid & 31;   // c quad
  const int ty = tid >> 5;   // t quad
  float acc[4][4] = {};
  const int sbeg = split * SLEN;
  for (int s0 = sbeg; s0 < sbeg + SLEN; s0 += 32) {
#pragma unroll
    for (int i = 0; i < 4; ++i) {
      int e = tid + i * 256;
      int k = e & 31, t = e >> 5;
      int s = s0 + k;
      float a = aggT[(size_t)(t0 + t) * NN + s];
      float sst = ssrc[s * NH + h];
      bool diag = (s == t0 + t);
      float ev = diag ? ma_sh[t] : a;
      bool adj = diag || (a > 0.f);
      float l = sst + sd_sh[t] + ev * ce;
      l = (l >= 0.f) ? l : NEG_SLOPE * l;
      PT[k][t] = adj ? __expf(l) : 0.f;
    }
#pragma unroll
    for (int i = 0; i < 16; ++i) {
      int e = tid + i * 256;
      int k = e >> 7, c = e & 127;
      Bs[k][c] = hfeat[(size_t)(s0 + k) * W + h * 128 + c];
    }
    __syncthreads();
    if (tid < 32) {
      float dl = 0.f;
#pragma unroll
      for (int k = 0; k < 32; ++k) dl += PT[k][tid];
      dloc[tid] += dl;
    }
#pragma unroll
    for (int k = 0; k < 32; ++k) {
      float4 pa = *(const float4*)&PT[k][ty * 4];
      float4 bv = *(const float4*)&Bs[k][tx * 4];
      acc[0][0] += pa.x * bv.x; acc[0][1] += pa.x * bv.y;
      acc[0][2] += pa.x * bv.z; acc[0][3] += pa.x * bv.w;
      acc[1][0] += pa.y * bv.x; acc[1][1] += pa.y * bv.y;
      acc[1][2] += pa.y * bv.z; acc[1][3] += pa.y * bv.w;
      acc[2][0] += pa.z * bv.x; acc[2][1] += pa.z * bv.y;
      acc[2][2] += pa.z * bv.z; acc[2][3] += pa.z * bv.w;
      acc[3][0] += pa.w * bv.x; acc[3][1] += pa.w * bv.y;
      acc[3][2] += pa.w * bv.z; acc[3][3] += pa.w * bv.w;
    }
    __syncthreads();
  }
#pragma unroll
  for (int i = 0; i < 4; ++i) {
    int t = ty * 4 + i;
    float4 v = make_float4(acc[i][0], acc[i][1], acc[i][2], acc[i][3]);
    *(float4*)&num[((size_t)split * NN + t0 + t) * W + h * 128 + tx * 4] = v;
  }
  if (tid < 32) dden[((size_t)split * NN + t0 + tid) * NH + h] = dloc[tid];
}

// ---------------------------------------------------------------------------
// Combine split-K partials: out = act( sum(num)/sum(d) + bias )
// ---------------------------------------------------------------------------
__global__ __launch_bounds__(256) void k_combine1(const float* __restrict__ num,
                                                  const float* __restrict__ dd,
                                                  const float* __restrict__ bias,
                                                  float* __restrict__ outf) {
  const size_t TOT = (size_t)NN * 512;
  for (size_t e = (size_t)blockIdx.x * 256 + threadIdx.x; e < TOT;
       e += (size_t)gridDim.x * 256) {
    int t = (int)(e >> 9), j = (int)(e & 511);
    int h = j >> 7;
    float nsum = num[e] + num[TOT + e];
    float dsum = dd[t * 4 + h] + dd[NN * 4 + t * 4 + h];
    float v = nsum / dsum + bias[j];
    outf[e] = v > 0.f ? v : 0.f;
  }
}

__global__ __launch_bounds__(256) void k_combine2(const float* __restrict__ num,
                                                  const float* __restrict__ dd,
                                                  const float* __restrict__ bias,
                                                  float* __restrict__ outf) {
  const size_t TOT = (size_t)NN * 128;
  for (size_t e = (size_t)blockIdx.x * 256 + threadIdx.x; e < TOT;
       e += (size_t)gridDim.x * 256) {
    int t = (int)(e >> 7), c = (int)(e & 127);
    float nsum = num[e] + num[TOT + e] + num[2 * TOT + e] + num[3 * TOT + e];
    float dsum = dd[t] + dd[NN + t] + dd[2 * NN + t] + dd[3 * NN + t];
    outf[e] = nsum / dsum + bias[c];
  }
}

// ---------------------------------------------------------------------------
// Segment mean pool (batch_idx sorted), one block per group
// ---------------------------------------------------------------------------
__global__ __launch_bounds__(128) void k_pool(const float* __restrict__ feat,
                                              const int* __restrict__ bidx,
                                              float* __restrict__ pooled) {
  const int g = blockIdx.x;
  __shared__ int lo[2];
  if (threadIdx.x == 0) { lo[0] = NN; lo[1] = NN; }
  __syncthreads();
  for (int n = threadIdx.x; n < NN; n += 128) {
    int b = bidx[n];
    int bprev = (n == 0) ? -1 : bidx[n - 1];
    if (b >= g && bprev < g) atomicMin(&lo[0], n);
    if (b >= g + 1 && bprev < g + 1) atomicMin(&lo[1], n);
  }
  __syncthreads();
  int s = lo[0], e = lo[1];
  float sum = 0.f;
  for (int n = s; n < e; ++n) sum += feat[(size_t)n * 128 + threadIdx.x];
  float cntf = (float)((e - s) > 1 ? (e - s) : 1);
  pooled[g * 128 + threadIdx.x] = sum / cntf;
}

// ---------------------------------------------------------------------------
// fc + log_softmax -> out[8][10]
// ---------------------------------------------------------------------------
__global__ __launch_bounds__(128) void k_head(const float* __restrict__ pooled,
                                              const float* __restrict__ fcw,
                                              const float* __restrict__ fcb,
                                              float* __restrict__ out) {
  __shared__ float logits[8][10];
  int tid = threadIdx.x;
  if (tid < 80) {
    int g = tid / 10, o = tid % 10;
    float s = fcb[o];
    for (int c = 0; c < 128; ++c) s += pooled[g * 128 + c] * fcw[c * 10 + o];
    logits[g][o] = s;
  }
  __syncthreads();
  if (tid < 80) {
    int g = tid / 10, o = tid % 10;
    float m = -1e30f;
    for (int i = 0; i < 10; ++i) m = fmaxf(m, logits[g][i]);
    float den = 0.f;
    for (int i = 0; i < 10; ++i) den += expf(logits[g][i] - m);
    out[tid] = logits[g][o] - m - logf(den);
  }
}

extern "C" void kernel_launch(void* const* d_in, const int* in_sizes, int n_in,
                              void* d_out, int out_size, void* d_ws,
                              size_t ws_size, hipStream_t stream) {
  (void)in_sizes; (void)n_in; (void)out_size; (void)ws_size;
  const float* x      = (const float*)d_in[0];
  const float* attn   = (const float*)d_in[1];
  const int*   bidx   = (const int*)d_in[2];
  const float* conv_w = (const float*)d_in[3];
  const float* conv_b = (const float*)d_in[4];
  const float* W1     = (const float*)d_in[5];
  const float* asrc1  = (const float*)d_in[6];
  const float* adst1  = (const float*)d_in[7];
  const float* aedge1 = (const float*)d_in[8];
  const float* We1    = (const float*)d_in[9];
  const float* b1     = (const float*)d_in[10];
  const float* W2     = (const float*)d_in[11];
  const float* asrc2  = (const float*)d_in[12];
  const float* adst2  = (const float*)d_in[13];
  const float* aedge2 = (const float*)d_in[14];
  const float* We2    = (const float*)d_in[15];
  const float* b2     = (const float*)d_in[16];
  const float* fcw    = (const float*)d_in[17];
  const float* fcb    = (const float*)d_in[18];

  float* ws = (float*)d_ws;
  float* aggT  = ws;                      // 4,194,304
  float* num1  = aggT + 4194304;          // 2,097,152
  float* h1    = num1 + 2097152;          // 1,048,576
  float* feat1 = h1 + 1048576;            // 1,048,576
  float* num2  = feat1 + 1048576;         // 1,048,576
  float* h2    = num2 + 1048576;          //   262,144
  float* feat2 = h2 + 262144;             //   262,144
  float* d1    = feat2 + 262144;          //    16,384
  float* d2    = d1 + 16384;              //     8,192
  float* ssrc1 = d2 + 8192;               //     8,192
  float* sdst1 = ssrc1 + 8192;            //     8,192
  float* ssrc2 = sdst1 + 8192;            //     2,048
  float* sdst2 = ssrc2 + 2048;            //     2,048
  float* mean_attr = sdst2 + 2048;        //     2,048
  float* ce    = mean_attr + 2048;        //         8
  float* pooled = ce + 8;                 //     1,024

  k_agg<<<dim3(32, 32), 256, 0, stream>>>(attn, conv_w, conv_b, aggT);
  k_stats<<<2048, 256, 0, stream>>>(aggT, mean_attr);
  k_prep<<<1, 256, 0, stream>>>(aedge1, We1, aedge2, We2, ce);
  k_gemm<64, 64, 32, 4, 4><<<dim3(512 / 64, 2048 / 64), 256, 0, stream>>>(
      x, W1, h1, 2048, 512, 128);
  k_srcdst<4><<<2048, 64, 0, stream>>>(h1, asrc1, adst1, ssrc1, sdst1);
  k_attn<4, 2><<<dim3(64, 4, 2), 256, 0, stream>>>(aggT, h1, ssrc1, sdst1,
                                                   mean_attr, ce, num1, d1);
  k_combine1<<<1024, 256, 0, stream>>>(num1, d1, b1, feat1);
  k_gemm<32, 32, 32, 2, 2><<<dim3(128 / 32, 2048 / 32), 256, 0, stream>>>(
      feat1, W2, h2, 2048, 128, 512);
  k_srcdst<1><<<2048, 64, 0, stream>>>(h2, asrc2, adst2, ssrc2, sdst2);
  k_attn<1, 4><<<dim3(64, 1, 4), 256, 0, stream>>>(aggT, h2, ssrc2, sdst2,
                                                   mean_attr, ce, num2, d2);
  k_combine2<<<512, 256, 0, stream>>>(num2, d2, b2, feat2);
  k_pool<<<8, 128, 0, stream>>>(feat2, bidx, pooled);
  k_head<<<1, 128, 0, stream>>>(pooled, fcw, fcb, (float*)d_out);
}

// Round 2
// 272.573 us; speedup vs baseline: 1.8592x; 1.8592x over previous
//
#include <hip/hip_runtime.h>
#include <hip/hip_bf16.h>
#include <math.h>

#define NN 2048
#define NEG_SLOPE 0.2f

typedef __attribute__((ext_vector_type(8))) short bf16x8;
typedef __attribute__((ext_vector_type(4))) float f32x4;

static __device__ inline short f2bf(float x) {
  union { float f; unsigned u; } v;
  v.f = x;
  unsigned r = v.u + 0x7fffu + ((v.u >> 16) & 1u);  // RNE
  return (short)(r >> 16);
}

// ---------------------------------------------------------------------------
// K1: agg[s,t] = sum_c conv_w[c]*attn[c,s,t] + conv_b ; store TRANSPOSED:
//     aggT[t][s].  Tiled 64x64 with LDS transpose, coalesced both ways.
// ---------------------------------------------------------------------------
__global__ __launch_bounds__(256) void k_agg(const float* __restrict__ attn,
                                             const float* __restrict__ conv_w,
                                             const float* __restrict__ conv_b,
                                             float* __restrict__ aggT) {
  __shared__ float tile[64][65];
  const int t0 = blockIdx.x * 64;
  const int s0 = blockIdx.y * 64;
  const int tx = threadIdx.x & 63;   // t within tile
  const int ty = threadIdx.x >> 6;   // 0..3
  float w[12];
#pragma unroll
  for (int c = 0; c < 12; ++c) w[c] = conv_w[c];
  const float cb = conv_b[0];
  float acc[16];
#pragma unroll
  for (int i = 0; i < 16; ++i) acc[i] = cb;
  for (int c = 0; c < 12; ++c) {
    const float* base = attn + (size_t)c * NN * NN + (size_t)s0 * NN + t0 + tx;
#pragma unroll
    for (int i = 0; i < 16; ++i) {
      int s = 4 * i + ty;
      acc[i] += w[c] * base[(size_t)s * NN];
    }
  }
#pragma unroll
  for (int i = 0; i < 16; ++i) tile[4 * i + ty][tx] = acc[i];
  __syncthreads();
  const int sx = tx;
#pragma unroll
  for (int i = 0; i < 16; ++i) {
    int t = 4 * i + ty;
    aggT[(size_t)(t0 + t) * NN + s0 + sx] = tile[sx][t];
  }
}

// ---------------------------------------------------------------------------
// K1b: per-target stats over aggT row: mean_attr[t] = sum(masked)/max(cnt,1)
// ---------------------------------------------------------------------------
__global__ __launch_bounds__(256) void k_stats(const float* __restrict__ aggT,
                                               float* __restrict__ mean_attr) {
  const int t = blockIdx.x;
  float sum = 0.f;
  int cnt = 0;
  for (int s = threadIdx.x; s < NN; s += 256) {
    float a = aggT[(size_t)t * NN + s];
    if (a > 0.f && s != t) { sum += a; cnt++; }
  }
  for (int off = 32; off; off >>= 1) {
    sum += __shfl_down(sum, off);
    cnt += __shfl_down(cnt, off);
  }
  __shared__ float swsum[4];
  __shared__ int swcnt[4];
  if ((threadIdx.x & 63) == 0) {
    swsum[threadIdx.x >> 6] = sum;
    swcnt[threadIdx.x >> 6] = cnt;
  }
  __syncthreads();
  if (threadIdx.x == 0) {
    float s = swsum[0] + swsum[1] + swsum[2] + swsum[3];
    int c = swcnt[0] + swcnt[1] + swcnt[2] + swcnt[3];
    mean_attr[t] = s / (float)(c > 1 ? c : 1);
  }
}

// ---------------------------------------------------------------------------
// K_prep: ce1[h] = sum_c att_edge1[h,c]*We1[h*128+c]  (h=0..3), ce[4] = layer2
// ---------------------------------------------------------------------------
__global__ __launch_bounds__(256) void k_prep(const float* __restrict__ ae1,
                                              const float* __restrict__ We1,
                                              const float* __restrict__ ae2,
                                              const float* __restrict__ We2,
                                              float* __restrict__ ce) {
  const int lane = threadIdx.x & 63;
  const int wv = threadIdx.x >> 6;
  float p = ae1[wv * 128 + lane] * We1[wv * 128 + lane] +
            ae1[wv * 128 + 64 + lane] * We1[wv * 128 + 64 + lane];
  for (int off = 32; off; off >>= 1) p += __shfl_down(p, off);
  if (lane == 0) ce[wv] = p;
  float q = ae2[lane] * We2[lane] + ae2[64 + lane] * We2[64 + lane];
  for (int off = 32; off; off >>= 1) q += __shfl_down(q, off);
  if (threadIdx.x == 0) ce[4] = q;
}

// ---------------------------------------------------------------------------
// Generic fp32 GEMM  C[M,N] = A[M,K] @ B[K,N]   (256 threads)
// ---------------------------------------------------------------------------
template <int BM, int BN, int BK, int TM, int TN>
__global__ __launch_bounds__(256) void k_gemm(const float* __restrict__ A,
                                              const float* __restrict__ B,
                                              float* __restrict__ C, int M,
                                              int Nn, int K) {
  __shared__ float As[BK][BM + 4];
  __shared__ float Bs[BK][BN + 4];
  const int tx = threadIdx.x % (BN / TN);
  const int ty = threadIdx.x / (BN / TN);
  const int n0 = blockIdx.x * BN;
  const int m0 = blockIdx.y * BM;
  float acc[TM][TN] = {};
  for (int k0 = 0; k0 < K; k0 += BK) {
    for (int e = threadIdx.x; e < BM * BK; e += 256) {
      int r = e / BK, c = e % BK;
      As[c][r] = A[(size_t)(m0 + r) * K + k0 + c];
    }
    for (int e = threadIdx.x; e < BK * BN; e += 256) {
      int r = e / BN, c = e % BN;
      Bs[r][c] = B[(size_t)(k0 + r) * Nn + n0 + c];
    }
    __syncthreads();
#pragma unroll
    for (int kk = 0; kk < BK; ++kk) {
      float a[TM], b[TN];
#pragma unroll
      for (int i = 0; i < TM; ++i) a[i] = As[kk][ty * TM + i];
#pragma unroll
      for (int j = 0; j < TN; ++j) b[j] = Bs[kk][tx * TN + j];
#pragma unroll
      for (int i = 0; i < TM; ++i)
#pragma unroll
        for (int j = 0; j < TN; ++j) acc[i][j] += a[i] * b[j];
    }
    __syncthreads();
  }
#pragma unroll
  for (int i = 0; i < TM; ++i)
#pragma unroll
    for (int j = 0; j < TN; ++j)
      C[(size_t)(m0 + ty * TM + i) * Nn + n0 + tx * TN + j] = acc[i][j];
}

// ---------------------------------------------------------------------------
// Transpose + bf16 convert: h[N][C] fp32 -> hT[C][N] bf16
// ---------------------------------------------------------------------------
__global__ __launch_bounds__(256) void k_t2b(const float* __restrict__ h,
                                             __hip_bfloat16* __restrict__ hT,
                                             int C) {
  __shared__ float tile[64][65];
  const int n0 = blockIdx.x * 64;
  const int c0 = blockIdx.y * 64;
  const int cx = threadIdx.x & 63;
  const int ry = threadIdx.x >> 6;
#pragma unroll
  for (int i = 0; i < 16; ++i) {
    int n = 4 * i + ry;
    tile[n][cx] = h[(size_t)(n0 + n) * C + c0 + cx];
  }
  __syncthreads();
#pragma unroll
  for (int i = 0; i < 16; ++i) {
    int c = 4 * i + ry;
    hT[(size_t)(c0 + c) * NN + n0 + cx] = __float2bfloat16(tile[cx][c]);
  }
}

// ---------------------------------------------------------------------------
// MFMA fused attention-softmax GEMM (numerator + denominator), split over s.
//   P[t,s] = adj ? exp(leaky(ssrc[s]+sdst[t]+eattr[t,s]*ce)) : 0
//   num[t,c] += P[t,s]*h[s,c] ;  d[t] += P[t,s]
// Block: 32 targets x 128 channels (one head), 4 waves in 2(M) x 2(N).
// A-frags (P) computed in registers from aggT; B-frags read from hT (bf16).
// mfma_f32_16x16x32_bf16: A lane l: row=l&15, k=(l>>4)*8+j (contig 8).
//                         B lane l: col=l&15, k=(l>>4)*8+j (contig 8 in hT row).
//                         C/D lane l: col=l&15, row=(l>>4)*4+reg.
// ---------------------------------------------------------------------------
template <int NH, int SPLITS>
__global__ __launch_bounds__(256) void k_attn_mfma(
    const float* __restrict__ aggT, const __hip_bfloat16* __restrict__ hT,
    const float* __restrict__ ssrc, const float* __restrict__ sdst,
    const float* __restrict__ mean_attr, const float* __restrict__ ce_all,
    float* __restrict__ num, float* __restrict__ dden) {
  constexpr int W = NH * 128;
  constexpr int SLEN = NN / SPLITS;
  const int t0 = blockIdx.x * 32;
  const int h = (NH == 1) ? 0 : blockIdx.y;
  const int split = blockIdx.z;
  const int sbeg = split * SLEN;
  const float ce = ce_all[(NH == 1) ? 4 : h];

  __shared__ float ss_sh[SLEN];
  for (int i = threadIdx.x; i < SLEN; i += 256)
    ss_sh[i] = ssrc[(sbeg + i) * NH + h];
  __syncthreads();

  const int tid = threadIdx.x;
  const int lane = tid & 63;
  const int w = tid >> 6;
  const int wm = w & 1;        // M half (16 targets each)
  const int wn = w >> 1;       // N half (64 cols each)
  const int m0 = t0 + wm * 16;
  const int row = lane & 15;   // A row / B col / C col
  const int kg = lane >> 4;    // k-group (0..3)
  const int tRow = m0 + row;

  const float sd_t = sdst[tRow * NH + h];
  const float ma_t = mean_attr[tRow];
  const float* arow = aggT + (size_t)tRow * NN;
  const __hip_bfloat16* bptr0 = hT + (size_t)(h * 128 + wn * 64 + row) * NN;

  f32x4 acc[4] = {{0.f, 0.f, 0.f, 0.f},
                  {0.f, 0.f, 0.f, 0.f},
                  {0.f, 0.f, 0.f, 0.f},
                  {0.f, 0.f, 0.f, 0.f}};
  float dpart = 0.f;

  for (int s0 = sbeg; s0 < sbeg + SLEN; s0 += 32) {
    const int sk = s0 + kg * 8;
    f32x4 a0 = *(const f32x4*)(arow + sk);
    f32x4 a1 = *(const f32x4*)(arow + sk + 4);
    f32x4 sv0 = *(const f32x4*)(ss_sh + (sk - sbeg));
    f32x4 sv1 = *(const f32x4*)(ss_sh + (sk - sbeg) + 4);
    float av[8] = {a0.x, a0.y, a0.z, a0.w, a1.x, a1.y, a1.z, a1.w};
    float sv[8] = {sv0.x, sv0.y, sv0.z, sv0.w, sv1.x, sv1.y, sv1.z, sv1.w};
    short pb[8];
#pragma unroll
    for (int j = 0; j < 8; ++j) {
      const int s = sk + j;
      const float a = av[j];
      const bool diag = (s == tRow);
      const float ev = diag ? ma_t : a;
      const bool adj = diag || (a > 0.f);
      float l = sv[j] + sd_t + ev * ce;
      l = (l >= 0.f) ? l : NEG_SLOPE * l;
      const float p = adj ? __expf(l) : 0.f;
      dpart += p;
      pb[j] = f2bf(p);
    }
    bf16x8 A = {pb[0], pb[1], pb[2], pb[3], pb[4], pb[5], pb[6], pb[7]};
#pragma unroll
    for (int f = 0; f < 4; ++f) {
      bf16x8 B = *(const bf16x8*)(bptr0 + (size_t)f * 16 * NN + sk);
      acc[f] = __builtin_amdgcn_mfma_f32_16x16x32_bf16(A, B, acc[f], 0, 0, 0);
    }
  }

  // denominator: reduce k-groups (same row across lane^16, lane^32)
  dpart += __shfl_xor(dpart, 16);
  dpart += __shfl_xor(dpart, 32);
  if (wn == 0 && lane < 16)
    dden[((size_t)split * NN + tRow) * NH + h] = dpart;

  // numerator write: C/D layout col=lane&15(row var), row=kg*4+r
#pragma unroll
  for (int f = 0; f < 4; ++f) {
    const int col = h * 128 + wn * 64 + f * 16 + row;
#pragma unroll
    for (int r = 0; r < 4; ++r) {
      const int trow = m0 + kg * 4 + r;
      num[((size_t)split * NN + trow) * W + col] = acc[f][r];
    }
  }
}

// ---------------------------------------------------------------------------
// Combine split-K partials: out = act( sum(num)/sum(d) + bias )
// ---------------------------------------------------------------------------
__global__ __launch_bounds__(256) void k_combine1(const float* __restrict__ num,
                                                  const float* __restrict__ dd,
                                                  const float* __restrict__ bias,
                                                  float* __restrict__ outf) {
  const size_t TOT = (size_t)NN * 512;
  for (size_t e = (size_t)blockIdx.x * 256 + threadIdx.x; e < TOT;
       e += (size_t)gridDim.x * 256) {
    int t = (int)(e >> 9), j = (int)(e & 511);
    int h = j >> 7;
    float nsum = num[e] + num[TOT + e];
    float dsum = dd[t * 4 + h] + dd[NN * 4 + t * 4 + h];
    float v = nsum / dsum + bias[j];
    outf[e] = v > 0.f ? v : 0.f;
  }
}

__global__ __launch_bounds__(256) void k_combine2(const float* __restrict__ num,
                                                  const float* __restrict__ dd,
                                                  const float* __restrict__ bias,
                                                  float* __restrict__ outf) {
  const size_t TOT = (size_t)NN * 128;
  for (size_t e = (size_t)blockIdx.x * 256 + threadIdx.x; e < TOT;
       e += (size_t)gridDim.x * 256) {
    int t = (int)(e >> 7), c = (int)(e & 127);
    float nsum = num[e] + num[TOT + e] + num[2 * TOT + e] + num[3 * TOT + e];
    float dsum = dd[t] + dd[NN + t] + dd[2 * NN + t] + dd[3 * NN + t];
    outf[e] = nsum / dsum + bias[c];
  }
}

// ---------------------------------------------------------------------------
// s_src / s_dst per node: dot(h[n, h*128:...], att_vec)
// ---------------------------------------------------------------------------
template <int NH>
__global__ __launch_bounds__(64) void k_srcdst(const float* __restrict__ h,
                                               const float* __restrict__ a_src,
                                               const float* __restrict__ a_dst,
                                               float* __restrict__ ssrc,
                                               float* __restrict__ sdst) {
  const int n = blockIdx.x;
  const int lane = threadIdx.x;
  float ps = 0.f, pd = 0.f;
  if constexpr (NH == 4) {
    const float4* hv = (const float4*)(h + (size_t)n * 512);
    const float4* av = (const float4*)a_src;
    const float4* dv = (const float4*)a_dst;
    float4 v0 = hv[lane * 2], v1 = hv[lane * 2 + 1];
    float4 a0 = av[lane * 2], a1 = av[lane * 2 + 1];
    float4 d0 = dv[lane * 2], d1 = dv[lane * 2 + 1];
    ps = v0.x * a0.x + v0.y * a0.y + v0.z * a0.z + v0.w * a0.w +
         v1.x * a1.x + v1.y * a1.y + v1.z * a1.z + v1.w * a1.w;
    pd = v0.x * d0.x + v0.y * d0.y + v0.z * d0.z + v0.w * d0.w +
         v1.x * d1.x + v1.y * d1.y + v1.z * d1.z + v1.w * d1.w;
    for (int off = 8; off; off >>= 1) {
      ps += __shfl_down(ps, off);
      pd += __shfl_down(pd, off);
    }
    if ((lane & 15) == 0) {
      int hh = lane >> 4;
      ssrc[n * 4 + hh] = ps;
      sdst[n * 4 + hh] = pd;
    }
  } else {
    const float2* hv = (const float2*)(h + (size_t)n * 128);
    const float2* av = (const float2*)a_src;
    const float2* dv = (const float2*)a_dst;
    float2 v = hv[lane];
    float2 a = av[lane];
    float2 d = dv[lane];
    ps = v.x * a.x + v.y * a.y;
    pd = v.x * d.x + v.y * d.y;
    for (int off = 32; off; off >>= 1) {
      ps += __shfl_down(ps, off);
      pd += __shfl_down(pd, off);
    }
    if (lane == 0) {
      ssrc[n] = ps;
      sdst[n] = pd;
    }
  }
}

// ---------------------------------------------------------------------------
// Segment mean pool (batch_idx sorted), one block per group
// ---------------------------------------------------------------------------
__global__ __launch_bounds__(128) void k_pool(const float* __restrict__ feat,
                                              const int* __restrict__ bidx,
                                              float* __restrict__ pooled) {
  const int g = blockIdx.x;
  __shared__ int lo[2];
  if (threadIdx.x == 0) { lo[0] = NN; lo[1] = NN; }
  __syncthreads();
  for (int n = threadIdx.x; n < NN; n += 128) {
    int b = bidx[n];
    int bprev = (n == 0) ? -1 : bidx[n - 1];
    if (b >= g && bprev < g) atomicMin(&lo[0], n);
    if (b >= g + 1 && bprev < g + 1) atomicMin(&lo[1], n);
  }
  __syncthreads();
  int s = lo[0], e = lo[1];
  float sum = 0.f;
  for (int n = s; n < e; ++n) sum += feat[(size_t)n * 128 + threadIdx.x];
  float cntf = (float)((e - s) > 1 ? (e - s) : 1);
  pooled[g * 128 + threadIdx.x] = sum / cntf;
}

// ---------------------------------------------------------------------------
// fc + log_softmax -> out[8][10]
// ---------------------------------------------------------------------------
__global__ __launch_bounds__(128) void k_head(const float* __restrict__ pooled,
                                              const float* __restrict__ fcw,
                                              const float* __restrict__ fcb,
                                              float* __restrict__ out) {
  __shared__ float logits[8][10];
  int tid = threadIdx.x;
  if (tid < 80) {
    int g = tid / 10, o = tid % 10;
    float s = fcb[o];
    for (int c = 0; c < 128; ++c) s += pooled[g * 128 + c] * fcw[c * 10 + o];
    logits[g][o] = s;
  }
  __syncthreads();
  if (tid < 80) {
    int g = tid / 10, o = tid % 10;
    float m = -1e30f;
    for (int i = 0; i < 10; ++i) m = fmaxf(m, logits[g][i]);
    float den = 0.f;
    for (int i = 0; i < 10; ++i) den += expf(logits[g][i] - m);
    out[tid] = logits[g][o] - m - logf(den);
  }
}

extern "C" void kernel_launch(void* const* d_in, const int* in_sizes, int n_in,
                              void* d_out, int out_size, void* d_ws,
                              size_t ws_size, hipStream_t stream) {
  (void)in_sizes; (void)n_in; (void)out_size; (void)ws_size;
  const float* x      = (const float*)d_in[0];
  const float* attn   = (const float*)d_in[1];
  const int*   bidx   = (const int*)d_in[2];
  const float* conv_w = (const float*)d_in[3];
  const float* conv_b = (const float*)d_in[4];
  const float* W1     = (const float*)d_in[5];
  const float* asrc1  = (const float*)d_in[6];
  const float* adst1  = (const float*)d_in[7];
  const float* aedge1 = (const float*)d_in[8];
  const float* We1    = (const float*)d_in[9];
  const float* b1     = (const float*)d_in[10];
  const float* W2     = (const float*)d_in[11];
  const float* asrc2  = (const float*)d_in[12];
  const float* adst2  = (const float*)d_in[13];
  const float* aedge2 = (const float*)d_in[14];
  const float* We2    = (const float*)d_in[15];
  const float* b2     = (const float*)d_in[16];
  const float* fcw    = (const float*)d_in[17];
  const float* fcb    = (const float*)d_in[18];

  float* ws = (float*)d_ws;
  float* aggT  = ws;                      // 4,194,304
  float* num1  = aggT + 4194304;          // 2,097,152
  float* h1    = num1 + 2097152;          // 1,048,576
  float* feat1 = h1 + 1048576;            // 1,048,576
  float* num2  = feat1 + 1048576;         // 1,048,576
  float* h2    = num2 + 1048576;          //   262,144
  float* feat2 = h2 + 262144;             //   262,144
  float* d1    = feat2 + 262144;          //    16,384
  float* d2    = d1 + 16384;              //     8,192
  float* ssrc1 = d2 + 8192;               //     8,192
  float* sdst1 = ssrc1 + 8192;            //     8,192
  float* ssrc2 = sdst1 + 8192;            //     2,048
  float* sdst2 = ssrc2 + 2048;            //     2,048
  float* mean_attr = sdst2 + 2048;        //     2,048
  float* ce    = mean_attr + 2048;        //         8
  float* pooled = ce + 8;                 //     1,024
  // bf16 transposed feature buffers alias dead fp32 regions:
  // hT1 (512x2048 bf16 = 524288 float-slots) lives in num2 (used only attn1;
  // num2 written only in attn2, after hT1 is dead).
  __hip_bfloat16* hT1 = (__hip_bfloat16*)num2;
  // hT2 (128x2048 bf16 = 131072 float-slots) lives in num1 (dead after
  // k_combine1, before k_t2b writes hT2).
  __hip_bfloat16* hT2 = (__hip_bfloat16*)num1;

  k_agg<<<dim3(32, 32), 256, 0, stream>>>(attn, conv_w, conv_b, aggT);
  k_stats<<<2048, 256, 0, stream>>>(aggT, mean_attr);
  k_prep<<<1, 256, 0, stream>>>(aedge1, We1, aedge2, We2, ce);
  k_gemm<64, 64, 32, 4, 4><<<dim3(512 / 64, 2048 / 64), 256, 0, stream>>>(
      x, W1, h1, 2048, 512, 128);
  k_srcdst<4><<<2048, 64, 0, stream>>>(h1, asrc1, adst1, ssrc1, sdst1);
  k_t2b<<<dim3(32, 8), 256, 0, stream>>>(h1, hT1, 512);
  k_attn_mfma<4, 2><<<dim3(64, 4, 2), 256, 0, stream>>>(
      aggT, hT1, ssrc1, sdst1, mean_attr, ce, num1, d1);
  k_combine1<<<1024, 256, 0, stream>>>(num1, d1, b1, feat1);
  k_gemm<32, 32, 32, 2, 2><<<dim3(128 / 32, 2048 / 32), 256, 0, stream>>>(
      feat1, W2, h2, 2048, 128, 512);
  k_srcdst<1><<<2048, 64, 0, stream>>>(h2, asrc2, adst2, ssrc2, sdst2);
  k_t2b<<<dim3(32, 2), 256, 0, stream>>>(h2, hT2, 128);
  k_attn_mfma<1, 4><<<dim3(64, 1, 4), 256, 0, stream>>>(
      aggT, hT2, ssrc2, sdst2, mean_attr, ce, num2, d2);
  k_combine2<<<512, 256, 0, stream>>>(num2, d2, b2, feat2);
  k_pool<<<8, 128, 0, stream>>>(feat2, bidx, pooled);
  k_head<<<1, 128, 0, stream>>>(pooled, fcw, fcb, (float*)d_out);
}

// Round 3
// 219.558 us; speedup vs baseline: 2.3081x; 1.2415x over previous
//
#include <hip/hip_runtime.h>
#include <hip/hip_bf16.h>
#include <math.h>

#define NN 2048
#define NEG_SLOPE 0.2f

typedef __attribute__((ext_vector_type(8))) short bf16x8;
typedef __attribute__((ext_vector_type(4))) float f32x4;

static __device__ inline short f2bf(float x) {
  union { float f; unsigned u; } v;
  v.f = x;
  unsigned r = v.u + 0x7fffu + ((v.u >> 16) & 1u);  // RNE
  return (short)(r >> 16);
}

// ---------------------------------------------------------------------------
// K1: agg[s,t] = sum_c conv_w[c]*attn[c,s,t] + conv_b ; store TRANSPOSED:
//     aggT[t][s].  Tiled 64x64 with LDS transpose, coalesced both ways.
// ---------------------------------------------------------------------------
__global__ __launch_bounds__(256) void k_agg(const float* __restrict__ attn,
                                             const float* __restrict__ conv_w,
                                             const float* __restrict__ conv_b,
                                             float* __restrict__ aggT) {
  __shared__ float tile[64][65];
  const int t0 = blockIdx.x * 64;
  const int s0 = blockIdx.y * 64;
  const int tx = threadIdx.x & 63;   // t within tile
  const int ty = threadIdx.x >> 6;   // 0..3
  float w[12];
#pragma unroll
  for (int c = 0; c < 12; ++c) w[c] = conv_w[c];
  const float cb = conv_b[0];
  float acc[16];
#pragma unroll
  for (int i = 0; i < 16; ++i) acc[i] = cb;
  for (int c = 0; c < 12; ++c) {
    const float* base = attn + (size_t)c * NN * NN + (size_t)s0 * NN + t0 + tx;
#pragma unroll
    for (int i = 0; i < 16; ++i) {
      int s = 4 * i + ty;
      acc[i] += w[c] * base[(size_t)s * NN];
    }
  }
#pragma unroll
  for (int i = 0; i < 16; ++i) tile[4 * i + ty][tx] = acc[i];
  __syncthreads();
  const int sx = tx;
#pragma unroll
  for (int i = 0; i < 16; ++i) {
    int t = 4 * i + ty;
    aggT[(size_t)(t0 + t) * NN + s0 + sx] = tile[sx][t];
  }
}

// ---------------------------------------------------------------------------
// K1b: per-target stats over aggT row: mean_attr[t] = sum(masked)/max(cnt,1)
// ---------------------------------------------------------------------------
__global__ __launch_bounds__(256) void k_stats(const float* __restrict__ aggT,
                                               float* __restrict__ mean_attr) {
  const int t = blockIdx.x;
  float sum = 0.f;
  int cnt = 0;
  for (int s = threadIdx.x; s < NN; s += 256) {
    float a = aggT[(size_t)t * NN + s];
    if (a > 0.f && s != t) { sum += a; cnt++; }
  }
  for (int off = 32; off; off >>= 1) {
    sum += __shfl_down(sum, off);
    cnt += __shfl_down(cnt, off);
  }
  __shared__ float swsum[4];
  __shared__ int swcnt[4];
  if ((threadIdx.x & 63) == 0) {
    swsum[threadIdx.x >> 6] = sum;
    swcnt[threadIdx.x >> 6] = cnt;
  }
  __syncthreads();
  if (threadIdx.x == 0) {
    float s = swsum[0] + swsum[1] + swsum[2] + swsum[3];
    int c = swcnt[0] + swcnt[1] + swcnt[2] + swcnt[3];
    mean_attr[t] = s / (float)(c > 1 ? c : 1);
  }
}

// ---------------------------------------------------------------------------
// K_prep: ce1[h] = sum_c att_edge1[h,c]*We1[h*128+c]  (h=0..3), ce[4] = layer2
// ---------------------------------------------------------------------------
__global__ __launch_bounds__(256) void k_prep(const float* __restrict__ ae1,
                                              const float* __restrict__ We1,
                                              const float* __restrict__ ae2,
                                              const float* __restrict__ We2,
                                              float* __restrict__ ce) {
  const int lane = threadIdx.x & 63;
  const int wv = threadIdx.x >> 6;
  float p = ae1[wv * 128 + lane] * We1[wv * 128 + lane] +
            ae1[wv * 128 + 64 + lane] * We1[wv * 128 + 64 + lane];
  for (int off = 32; off; off >>= 1) p += __shfl_down(p, off);
  if (lane == 0) ce[wv] = p;
  float q = ae2[lane] * We2[lane] + ae2[64 + lane] * We2[64 + lane];
  for (int off = 32; off; off >>= 1) q += __shfl_down(q, off);
  if (threadIdx.x == 0) ce[4] = q;
}

// ---------------------------------------------------------------------------
// x fp32 -> bf16 elementwise (262144 elems)
// ---------------------------------------------------------------------------
__global__ __launch_bounds__(256) void k_xb(const float* __restrict__ in,
                                            __hip_bfloat16* __restrict__ out) {
  const int i = (blockIdx.x * 256 + threadIdx.x) * 4;
  float4 v = *(const float4*)(in + i);
  short4 o;
  o.x = f2bf(v.x); o.y = f2bf(v.y); o.z = f2bf(v.z); o.w = f2bf(v.w);
  *(short4*)((short*)out + i) = o;
}

// ---------------------------------------------------------------------------
// Generic transpose+bf16: in[R][C] fp32 -> out[C][R] bf16  (R,C mult of 64)
// ---------------------------------------------------------------------------
__global__ __launch_bounds__(256) void k_tbgen(const float* __restrict__ in,
                                               __hip_bfloat16* __restrict__ out,
                                               int R, int C) {
  __shared__ float tile[64][65];
  const int r0 = blockIdx.x * 64;
  const int c0 = blockIdx.y * 64;
  const int cx = threadIdx.x & 63;
  const int ry = threadIdx.x >> 6;
#pragma unroll
  for (int i = 0; i < 16; ++i) {
    int r = 4 * i + ry;
    tile[r][cx] = in[(size_t)(r0 + r) * C + c0 + cx];
  }
  __syncthreads();
#pragma unroll
  for (int i = 0; i < 16; ++i) {
    int c = 4 * i + ry;
    out[(size_t)(c0 + c) * R + r0 + cx] = __float2bfloat16(tile[cx][c]);
  }
}

// ---------------------------------------------------------------------------
// MFMA GEMM: C[M,N] = A[M,K] @ BT[N,K]^T ; also CT[N,M] bf16 (fused transpose).
// One wave per block: 16 rows x 64 cols, mfma_f32_16x16x32_bf16.
// ---------------------------------------------------------------------------
template <int KSTEPS>
__global__ __launch_bounds__(64) void k_gemm_bf(
    const __hip_bfloat16* __restrict__ A, const __hip_bfloat16* __restrict__ BT,
    float* __restrict__ C, __hip_bfloat16* __restrict__ CT, int M, int Nn,
    int K) {
  const int m0 = blockIdx.x * 16;
  const int n0 = blockIdx.y * 64;
  const int lane = threadIdx.x;
  const int row = lane & 15;
  const int kg = lane >> 4;
  const __hip_bfloat16* arow = A + (size_t)(m0 + row) * K + kg * 8;
  f32x4 acc[4] = {{0.f, 0.f, 0.f, 0.f},
                  {0.f, 0.f, 0.f, 0.f},
                  {0.f, 0.f, 0.f, 0.f},
                  {0.f, 0.f, 0.f, 0.f}};
#pragma unroll
  for (int ks = 0; ks < KSTEPS; ++ks) {
    bf16x8 Af = *(const bf16x8*)(arow + ks * 32);
#pragma unroll
    for (int f = 0; f < 4; ++f) {
      const __hip_bfloat16* bp =
          BT + (size_t)(n0 + f * 16 + row) * K + kg * 8 + ks * 32;
      bf16x8 Bf = *(const bf16x8*)bp;
      acc[f] = __builtin_amdgcn_mfma_f32_16x16x32_bf16(Af, Bf, acc[f], 0, 0, 0);
    }
  }
#pragma unroll
  for (int f = 0; f < 4; ++f) {
    const int col = n0 + f * 16 + row;
    short4 ct;
#pragma unroll
    for (int r = 0; r < 4; ++r) {
      const int trow = m0 + kg * 4 + r;
      C[(size_t)trow * Nn + col] = acc[f][r];
    }
    ct.x = f2bf(acc[f][0]); ct.y = f2bf(acc[f][1]);
    ct.z = f2bf(acc[f][2]); ct.w = f2bf(acc[f][3]);
    *(short4*)((short*)CT + (size_t)col * M + m0 + kg * 4) = ct;
  }
}

// ---------------------------------------------------------------------------
// s_src / s_dst per node: dot(h[n, h*128:...], att_vec)
// ---------------------------------------------------------------------------
template <int NH>
__global__ __launch_bounds__(64) void k_srcdst(const float* __restrict__ h,
                                               const float* __restrict__ a_src,
                                               const float* __restrict__ a_dst,
                                               float* __restrict__ ssrc,
                                               float* __restrict__ sdst) {
  const int n = blockIdx.x;
  const int lane = threadIdx.x;
  float ps = 0.f, pd = 0.f;
  if constexpr (NH == 4) {
    const float4* hv = (const float4*)(h + (size_t)n * 512);
    const float4* av = (const float4*)a_src;
    const float4* dv = (const float4*)a_dst;
    float4 v0 = hv[lane * 2], v1 = hv[lane * 2 + 1];
    float4 a0 = av[lane * 2], a1 = av[lane * 2 + 1];
    float4 d0 = dv[lane * 2], d1 = dv[lane * 2 + 1];
    ps = v0.x * a0.x + v0.y * a0.y + v0.z * a0.z + v0.w * a0.w +
         v1.x * a1.x + v1.y * a1.y + v1.z * a1.z + v1.w * a1.w;
    pd = v0.x * d0.x + v0.y * d0.y + v0.z * d0.z + v0.w * d0.w +
         v1.x * d1.x + v1.y * d1.y + v1.z * d1.z + v1.w * d1.w;
    for (int off = 8; off; off >>= 1) {
      ps += __shfl_down(ps, off);
      pd += __shfl_down(pd, off);
    }
    if ((lane & 15) == 0) {
      int hh = lane >> 4;
      ssrc[n * 4 + hh] = ps;
      sdst[n * 4 + hh] = pd;
    }
  } else {
    const float2* hv = (const float2*)(h + (size_t)n * 128);
    const float2* av = (const float2*)a_src;
    const float2* dv = (const float2*)a_dst;
    float2 v = hv[lane];
    float2 a = av[lane];
    float2 d = dv[lane];
    ps = v.x * a.x + v.y * a.y;
    pd = v.x * d.x + v.y * d.y;
    for (int off = 32; off; off >>= 1) {
      ps += __shfl_down(ps, off);
      pd += __shfl_down(pd, off);
    }
    if (lane == 0) {
      ssrc[n] = ps;
      sdst[n] = pd;
    }
  }
}

// ---------------------------------------------------------------------------
// Layer-1 fused attention: 4 waves = 4 heads sharing the same 16 target rows
// (aggT row loads hit L1 across waves). Per wave: 16 t x 128 cols, 8 frags.
// ---------------------------------------------------------------------------
template <int SPLITS>
__global__ __launch_bounds__(256) void k_attn1(
    const float* __restrict__ aggT, const __hip_bfloat16* __restrict__ hT,
    const float* __restrict__ ssrc, const float* __restrict__ sdst,
    const float* __restrict__ mean_attr, const float* __restrict__ ce_all,
    float* __restrict__ num, float* __restrict__ dden) {
  constexpr int SLEN = NN / SPLITS;
  const int t0 = blockIdx.x * 16;
  const int split = blockIdx.y;
  const int sbeg = split * SLEN;

  __shared__ float ss_sh[4 * SLEN];
  for (int i = threadIdx.x; i < 4 * SLEN; i += 256) {
    int hh = i / SLEN, s = i % SLEN;
    ss_sh[hh * SLEN + s] = ssrc[(sbeg + s) * 4 + hh];
  }
  __syncthreads();

  const int tid = threadIdx.x;
  const int lane = tid & 63;
  const int h = tid >> 6;       // wave = head
  const int row = lane & 15;
  const int kg = lane >> 4;
  const int tRow = t0 + row;

  const float ce = ce_all[h];
  const float sd_t = sdst[tRow * 4 + h];
  const float ma_t = mean_attr[tRow];
  const float* arow = aggT + (size_t)tRow * NN;
  const float* ssh = ss_sh + h * SLEN;
  const __hip_bfloat16* bbase = hT + (size_t)(h * 128 + row) * NN;

  f32x4 acc[8];
#pragma unroll
  for (int f = 0; f < 8; ++f) acc[f] = (f32x4){0.f, 0.f, 0.f, 0.f};
  float dpart = 0.f;

  for (int s0 = sbeg; s0 < sbeg + SLEN; s0 += 32) {
    const int sk = s0 + kg * 8;
    f32x4 a0 = *(const f32x4*)(arow + sk);
    f32x4 a1 = *(const f32x4*)(arow + sk + 4);
    f32x4 sv0 = *(const f32x4*)(ssh + (sk - sbeg));
    f32x4 sv1 = *(const f32x4*)(ssh + (sk - sbeg) + 4);
    float av[8] = {a0.x, a0.y, a0.z, a0.w, a1.x, a1.y, a1.z, a1.w};
    float sv[8] = {sv0.x, sv0.y, sv0.z, sv0.w, sv1.x, sv1.y, sv1.z, sv1.w};
    short pb[8];
#pragma unroll
    for (int j = 0; j < 8; ++j) {
      const int s = sk + j;
      const float a = av[j];
      const bool diag = (s == tRow);
      const float ev = diag ? ma_t : a;
      const bool adj = diag || (a > 0.f);
      float l = sv[j] + sd_t + ev * ce;
      l = fmaxf(l, NEG_SLOPE * l);
      const float p = adj ? __expf(l) : 0.f;
      dpart += p;
      pb[j] = f2bf(p);
    }
    bf16x8 A = {pb[0], pb[1], pb[2], pb[3], pb[4], pb[5], pb[6], pb[7]};
#pragma unroll
    for (int f = 0; f < 8; ++f) {
      bf16x8 B = *(const bf16x8*)(bbase + (size_t)f * 16 * NN + sk);
      acc[f] = __builtin_amdgcn_mfma_f32_16x16x32_bf16(A, B, acc[f], 0, 0, 0);
    }
  }

  dpart += __shfl_xor(dpart, 16);
  dpart += __shfl_xor(dpart, 32);
  if (lane < 16) dden[((size_t)split * NN + tRow) * 4 + h] = dpart;

#pragma unroll
  for (int f = 0; f < 8; ++f) {
    const int col = h * 128 + f * 16 + row;
#pragma unroll
    for (int r = 0; r < 4; ++r) {
      const int trow = t0 + kg * 4 + r;
      num[((size_t)split * NN + trow) * 512 + col] = acc[f][r];
    }
  }
}

// ---------------------------------------------------------------------------
// Layer-2 fused attention (1 head): 4 waves 2Mx2N over 32 targets x 128 cols.
// ---------------------------------------------------------------------------
template <int SPLITS>
__global__ __launch_bounds__(256) void k_attn2(
    const float* __restrict__ aggT, const __hip_bfloat16* __restrict__ hT,
    const float* __restrict__ ssrc, const float* __restrict__ sdst,
    const float* __restrict__ mean_attr, const float* __restrict__ ce_all,
    float* __restrict__ num, float* __restrict__ dden) {
  constexpr int SLEN = NN / SPLITS;
  const int t0 = blockIdx.x * 32;
  const int split = blockIdx.z;
  const int sbeg = split * SLEN;
  const float ce = ce_all[4];

  __shared__ float ss_sh[SLEN];
  for (int i = threadIdx.x; i < SLEN; i += 256) ss_sh[i] = ssrc[sbeg + i];
  __syncthreads();

  const int tid = threadIdx.x;
  const int lane = tid & 63;
  const int w = tid >> 6;
  const int wm = w & 1;
  const int wn = w >> 1;
  const int m0 = t0 + wm * 16;
  const int row = lane & 15;
  const int kg = lane >> 4;
  const int tRow = m0 + row;

  const float sd_t = sdst[tRow];
  const float ma_t = mean_attr[tRow];
  const float* arow = aggT + (size_t)tRow * NN;
  const __hip_bfloat16* bptr0 = hT + (size_t)(wn * 64 + row) * NN;

  f32x4 acc[4];
#pragma unroll
  for (int f = 0; f < 4; ++f) acc[f] = (f32x4){0.f, 0.f, 0.f, 0.f};
  float dpart = 0.f;

  for (int s0 = sbeg; s0 < sbeg + SLEN; s0 += 32) {
    const int sk = s0 + kg * 8;
    f32x4 a0 = *(const f32x4*)(arow + sk);
    f32x4 a1 = *(const f32x4*)(arow + sk + 4);
    f32x4 sv0 = *(const f32x4*)(ss_sh + (sk - sbeg));
    f32x4 sv1 = *(const f32x4*)(ss_sh + (sk - sbeg) + 4);
    float av[8] = {a0.x, a0.y, a0.z, a0.w, a1.x, a1.y, a1.z, a1.w};
    float sv[8] = {sv0.x, sv0.y, sv0.z, sv0.w, sv1.x, sv1.y, sv1.z, sv1.w};
    short pb[8];
#pragma unroll
    for (int j = 0; j < 8; ++j) {
      const int s = sk + j;
      const float a = av[j];
      const bool diag = (s == tRow);
      const float ev = diag ? ma_t : a;
      const bool adj = diag || (a > 0.f);
      float l = sv[j] + sd_t + ev * ce;
      l = fmaxf(l, NEG_SLOPE * l);
      const float p = adj ? __expf(l) : 0.f;
      dpart += p;
      pb[j] = f2bf(p);
    }
    bf16x8 A = {pb[0], pb[1], pb[2], pb[3], pb[4], pb[5], pb[6], pb[7]};
#pragma unroll
    for (int f = 0; f < 4; ++f) {
      bf16x8 B = *(const bf16x8*)(bptr0 + (size_t)f * 16 * NN + sk);
      acc[f] = __builtin_amdgcn_mfma_f32_16x16x32_bf16(A, B, acc[f], 0, 0, 0);
    }
  }

  dpart += __shfl_xor(dpart, 16);
  dpart += __shfl_xor(dpart, 32);
  if (wn == 0 && lane < 16) dden[(size_t)split * NN + tRow] = dpart;

#pragma unroll
  for (int f = 0; f < 4; ++f) {
    const int col = wn * 64 + f * 16 + row;
#pragma unroll
    for (int r = 0; r < 4; ++r) {
      const int trow = m0 + kg * 4 + r;
      num[((size_t)split * NN + trow) * 128 + col] = acc[f][r];
    }
  }
}

// ---------------------------------------------------------------------------
// Combine split partials: layer1 -> ReLU -> bf16 feat1 ; layer2 -> fp32 feat2
// ---------------------------------------------------------------------------
template <int S>
__global__ __launch_bounds__(256) void k_combine1(const float* __restrict__ num,
                                                  const float* __restrict__ dd,
                                                  const float* __restrict__ bias,
                                                  __hip_bfloat16* __restrict__ outf) {
  const size_t TOT = (size_t)NN * 512;
  for (size_t e = (size_t)blockIdx.x * 256 + threadIdx.x; e < TOT;
       e += (size_t)gridDim.x * 256) {
    int t = (int)(e >> 9), j = (int)(e & 511);
    int h = j >> 7;
    float nsum = 0.f, dsum = 0.f;
#pragma unroll
    for (int p = 0; p < S; ++p) nsum += num[(size_t)p * TOT + e];
#pragma unroll
    for (int p = 0; p < S; ++p) dsum += dd[((size_t)p * NN + t) * 4 + h];
    float v = nsum / dsum + bias[j];
    outf[e] = __float2bfloat16(v > 0.f ? v : 0.f);
  }
}

template <int S>
__global__ __launch_bounds__(256) void k_combine2(const float* __restrict__ num,
                                                  const float* __restrict__ dd,
                                                  const float* __restrict__ bias,
                                                  float* __restrict__ outf) {
  const size_t TOT = (size_t)NN * 128;
  for (size_t e = (size_t)blockIdx.x * 256 + threadIdx.x; e < TOT;
       e += (size_t)gridDim.x * 256) {
    int t = (int)(e >> 7), c = (int)(e & 127);
    float nsum = 0.f, dsum = 0.f;
#pragma unroll
    for (int p = 0; p < S; ++p) nsum += num[(size_t)p * TOT + e];
#pragma unroll
    for (int p = 0; p < S; ++p) dsum += dd[(size_t)p * NN + t];
    outf[e] = nsum / dsum + bias[c];
  }
}

// ---------------------------------------------------------------------------
// Segment mean pool (batch_idx sorted), one block per group
// ---------------------------------------------------------------------------
__global__ __launch_bounds__(128) void k_pool(const float* __restrict__ feat,
                                              const int* __restrict__ bidx,
                                              float* __restrict__ pooled) {
  const int g = blockIdx.x;
  __shared__ int lo[2];
  if (threadIdx.x == 0) { lo[0] = NN; lo[1] = NN; }
  __syncthreads();
  for (int n = threadIdx.x; n < NN; n += 128) {
    int b = bidx[n];
    int bprev = (n == 0) ? -1 : bidx[n - 1];
    if (b >= g && bprev < g) atomicMin(&lo[0], n);
    if (b >= g + 1 && bprev < g + 1) atomicMin(&lo[1], n);
  }
  __syncthreads();
  int s = lo[0], e = lo[1];
  float sum = 0.f;
  for (int n = s; n < e; ++n) sum += feat[(size_t)n * 128 + threadIdx.x];
  float cntf = (float)((e - s) > 1 ? (e - s) : 1);
  pooled[g * 128 + threadIdx.x] = sum / cntf;
}

// ---------------------------------------------------------------------------
// fc + log_softmax -> out[8][10]
// ---------------------------------------------------------------------------
__global__ __launch_bounds__(128) void k_head(const float* __restrict__ pooled,
                                              const float* __restrict__ fcw,
                                              const float* __restrict__ fcb,
                                              float* __restrict__ out) {
  __shared__ float logits[8][10];
  int tid = threadIdx.x;
  if (tid < 80) {
    int g = tid / 10, o = tid % 10;
    float s = fcb[o];
    for (int c = 0; c < 128; ++c) s += pooled[g * 128 + c] * fcw[c * 10 + o];
    logits[g][o] = s;
  }
  __syncthreads();
  if (tid < 80) {
    int g = tid / 10, o = tid % 10;
    float m = -1e30f;
    for (int i = 0; i < 10; ++i) m = fmaxf(m, logits[g][i]);
    float den = 0.f;
    for (int i = 0; i < 10; ++i) den += expf(logits[g][i] - m);
    out[tid] = logits[g][o] - m - logf(den);
  }
}

extern "C" void kernel_launch(void* const* d_in, const int* in_sizes, int n_in,
                              void* d_out, int out_size, void* d_ws,
                              size_t ws_size, hipStream_t stream) {
  (void)in_sizes; (void)n_in; (void)out_size; (void)ws_size;
  const float* x      = (const float*)d_in[0];
  const float* attn   = (const float*)d_in[1];
  const int*   bidx   = (const int*)d_in[2];
  const float* conv_w = (const float*)d_in[3];
  const float* conv_b = (const float*)d_in[4];
  const float* W1     = (const float*)d_in[5];
  const float* asrc1  = (const float*)d_in[6];
  const float* adst1  = (const float*)d_in[7];
  const float* aedge1 = (const float*)d_in[8];
  const float* We1    = (const float*)d_in[9];
  const float* b1     = (const float*)d_in[10];
  const float* W2     = (const float*)d_in[11];
  const float* asrc2  = (const float*)d_in[12];
  const float* adst2  = (const float*)d_in[13];
  const float* aedge2 = (const float*)d_in[14];
  const float* We2    = (const float*)d_in[15];
  const float* b2     = (const float*)d_in[16];
  const float* fcw    = (const float*)d_in[17];
  const float* fcb    = (const float*)d_in[18];

  float* ws = (float*)d_ws;
  float* aggT  = ws;                        // 4,194,304
  float* num1  = aggT + 4194304;            // 4,194,304 (4 splits x 2048 x 512)
  float* h1    = num1 + 4194304;            // 1,048,576
  float* num2  = h1 + 1048576;              // 2,097,152 (8 splits x 2048 x 128)
  float* h2    = num2 + 2097152;            //   262,144
  float* feat2 = h2 + 262144;               //   262,144
  float* d1    = feat2 + 262144;            //    32,768 (4 x 2048 x 4)
  float* d2    = d1 + 32768;                //    16,384 (8 x 2048)
  float* ssrc1 = d2 + 16384;                //     8,192
  float* sdst1 = ssrc1 + 8192;              //     8,192
  float* ssrc2 = sdst1 + 8192;              //     2,048
  float* sdst2 = ssrc2 + 2048;              //     2,048
  float* mean_attr = sdst2 + 2048;          //     2,048
  float* ce    = mean_attr + 2048;          //       256
  float* pooled = ce + 256;                 //     1,024
  float* bf_region = pooled + 1024;
  __hip_bfloat16* xb    = (__hip_bfloat16*)bf_region;          // 262,144 el
  __hip_bfloat16* w1t   = (__hip_bfloat16*)(bf_region + 131072);   // 65,536 el
  __hip_bfloat16* w2t   = (__hip_bfloat16*)(bf_region + 163840);   // 65,536 el
  __hip_bfloat16* hT1   = (__hip_bfloat16*)(bf_region + 196608);   // 1,048,576 el
  __hip_bfloat16* hT2   = (__hip_bfloat16*)(bf_region + 720896);   // 262,144 el
  __hip_bfloat16* feat1b = (__hip_bfloat16*)(bf_region + 851968);  // 1,048,576 el

  k_agg<<<dim3(32, 32), 256, 0, stream>>>(attn, conv_w, conv_b, aggT);
  k_stats<<<2048, 256, 0, stream>>>(aggT, mean_attr);
  k_prep<<<1, 256, 0, stream>>>(aedge1, We1, aedge2, We2, ce);
  k_xb<<<256, 256, 0, stream>>>(x, xb);
  k_tbgen<<<dim3(2, 8), 256, 0, stream>>>(W1, w1t, 128, 512);
  k_tbgen<<<dim3(8, 2), 256, 0, stream>>>(W2, w2t, 512, 128);
  k_gemm_bf<4><<<dim3(128, 8), 64, 0, stream>>>(xb, w1t, h1, hT1, 2048, 512, 128);
  k_srcdst<4><<<2048, 64, 0, stream>>>(h1, asrc1, adst1, ssrc1, sdst1);
  k_attn1<4><<<dim3(128, 4), 256, 0, stream>>>(aggT, hT1, ssrc1, sdst1,
                                               mean_attr, ce, num1, d1);
  k_combine1<4><<<1024, 256, 0, stream>>>(num1, d1, b1, feat1b);
  k_gemm_bf<16><<<dim3(128, 2), 64, 0, stream>>>(feat1b, w2t, h2, hT2, 2048,
                                                 128, 512);
  k_srcdst<1><<<2048, 64, 0, stream>>>(h2, asrc2, adst2, ssrc2, sdst2);
  k_attn2<8><<<dim3(64, 1, 8), 256, 0, stream>>>(aggT, hT2, ssrc2, sdst2,
                                                 mean_attr, ce, num2, d2);
  k_combine2<8><<<512, 256, 0, stream>>>(num2, d2, b2, feat2);
  k_pool<<<8, 128, 0, stream>>>(feat2, bidx, pooled);
  k_head<<<1, 128, 0, stream>>>(pooled, fcw, fcb, (float*)d_out);
}